// Round 4
// baseline (191.842 us; speedup 1.0000x reference)
//
#include <hip/hip_runtime.h>
#include <math.h>

// out[n,d] = sum_k basis(t_n)[k] * W[vid_n, d, k];  V=128, D=64, K=13.
// One fused kernel. Block-local bucket-by-video (LDS), basis in LDS (fp32),
// phase 2: lane = (n_sub, d-quad) -> float4 stores, weights in 52 VGPRs per
// lane reloaded only on (cluster-uniform) video transition along sorted list.

#define V 128
#define D 64
#define K 13
#define CHUNK 512         // n's per block (512*16*4B basis = 32KB -> 4 blocks/CU)
#define BS 256            // threads per block
#define PER (CHUNK / BS)  // 2 n's per thread in phase 1
#define BST 16            // basis row stride in floats (16B-aligned float4 rows)

__global__ __launch_bounds__(256, 4) void fused_kernel(
    const float* __restrict__ times, const int* __restrict__ ids,
    const float* __restrict__ weights, float* __restrict__ out, int n)
{
    __shared__ float basis[CHUNK * BST];        // 32 KB
    __shared__ unsigned short list[CHUNK];      // 1 KB: (li<<7)|v packed
    __shared__ int cnt[V];
    __shared__ int start[V];
    __shared__ int cur[V];

    int tid = threadIdx.x;
    int base = blockIdx.x * CHUNK;
    int total = n - base; if (total > CHUNK) total = CHUNK;  // valid n's this block

    if (tid < V) cnt[tid] = 0;
    __syncthreads();

    // ---- Phase 1: coalesced loads, basis -> LDS, count videos ----
    int myv[PER];
#pragma unroll
    for (int i = 0; i < PER; ++i) {
        int li = i * BS + tid;
        int g = base + li;
        myv[i] = -1;
        if (g < n) {
            float t = times[g];
            int v = ids[g];
            myv[i] = v;
            atomicAdd(&cnt[v], 1);
            float s, c;
            __sincosf(3.14159265358979323846f * t, &s, &c);
            float sa[6], ca[6];
            sa[0] = s; ca[0] = c;
#pragma unroll
            for (int j = 1; j < 6; ++j) {       // double-angle recurrence
                sa[j] = 2.0f * sa[j - 1] * ca[j - 1];
                ca[j] = 1.0f - 2.0f * sa[j - 1] * sa[j - 1];
            }
            float4* bp = (float4*)&basis[li * BST];
            bp[0] = make_float4(1.0f, sa[0], sa[1], sa[2]);
            bp[1] = make_float4(sa[3], sa[4], sa[5], ca[0]);
            bp[2] = make_float4(ca[1], ca[2], ca[3], ca[4]);
            basis[li * BST + 12] = ca[5];
        }
    }
    __syncthreads();

    // ---- Exclusive scan of cnt -> start ----
    if (tid < V) start[tid] = cnt[tid];
    __syncthreads();
    for (int off = 1; off < V; off <<= 1) {
        int val = 0;
        if (tid < V && tid >= off) val = start[tid - off];
        __syncthreads();
        if (tid < V) start[tid] += val;
        __syncthreads();
    }
    if (tid < V) { start[tid] -= cnt[tid]; cur[tid] = 0; }
    __syncthreads();

    // ---- Place packed (li, v) into sorted order ----
#pragma unroll
    for (int i = 0; i < PER; ++i) {
        if (myv[i] >= 0) {
            int li = i * BS + tid;
            int r = atomicAdd(&cur[myv[i]], 1);
            list[start[myv[i]] + r] = (unsigned short)((li << 7) | myv[i]);
        }
    }
    __syncthreads();

    // ---- Phase 2: wave walks 128 sorted entries, 4 per iter.
    //      lane = n_sub*16 + dq; lane computes out[n(n_sub), dq*4 .. dq*4+3]. ----
    int wave = tid >> 6;
    int lane = tid & 63;
    int n_sub = lane >> 4;       // which of the 4 n's this iter
    int dq = lane & 15;          // d-quad: d = dq*4
    int j0 = wave * (CHUNK / 4);
    int j1 = (wave + 1) * (CHUNK / 4); if (j1 > total) j1 = total;

    int vcur = -1;
    float wf[52];                // W[v][dq*4 .. dq*4+3][0..12] register cache
    for (int j = j0; j < j1; j += 4) {
        int jj = j + n_sub;
        bool valid = (jj < j1);
        unsigned int e = valid ? (unsigned int)list[jj] : 0u;  // 16-way broadcast read
        int li = (int)(e >> 7);
        int v = (int)(e & 127u);
        if (valid && v != vcur) {            // cluster-uniform; rare after sort
            vcur = v;
            const float4* wp = (const float4*)(weights + (v * D + dq * 4) * K);
#pragma unroll
            for (int q = 0; q < 13; ++q) *((float4*)&wf[q * 4]) = wp[q];
        }
        const float4* bp = (const float4*)&basis[li * BST];
        float4 b0 = bp[0], b1 = bp[1], b2 = bp[2];
        float bk12 = basis[li * BST + 12];
        float bk[13] = { b0.x, b0.y, b0.z, b0.w, b1.x, b1.y, b1.z, b1.w,
                         b2.x, b2.y, b2.z, b2.w, bk12 };
        float4 acc;
        float* ap = &acc.x;
#pragma unroll
        for (int dd = 0; dd < 4; ++dd) {
            const float* w = &wf[dd * 13];
            ap[dd] = ((bk[0] * w[0] + bk[1] * w[1]) + (bk[2] * w[2] + bk[3] * w[3]))
                   + ((bk[4] * w[4] + bk[5] * w[5]) + (bk[6] * w[6] + bk[7] * w[7]))
                   + (((bk[8] * w[8] + bk[9] * w[9]) + (bk[10] * w[10] + bk[11] * w[11]))
                      + bk[12] * w[12]);
        }
        if (valid)
            *(float4*)(out + (long)(base + li) * D + dq * 4) = acc;  // 16B/lane store
    }
}

extern "C" void kernel_launch(void* const* d_in, const int* in_sizes, int n_in,
                              void* d_out, int out_size, void* d_ws, size_t ws_size,
                              hipStream_t stream) {
    const float* times = (const float*)d_in[0];
    const int* ids = (const int*)d_in[1];
    const float* weights = (const float*)d_in[2];
    float* out = (float*)d_out;
    int n = in_sizes[0];

    int nblk = (n + CHUNK - 1) / CHUNK;   // 782 blocks @ n=400000
    fused_kernel<<<nblk, BS, 0, stream>>>(times, ids, weights, out, n);
}

// Round 6
// 146.594 us; speedup vs baseline: 1.3087x; 1.3087x over previous
//
#include <hip/hip_runtime.h>
#include <math.h>

// out[n,d] = sum_k basis(t_n)[k] * W[vid_n, d, k];  V=128, D=64, K=13.
// One fused kernel, wave-per-n in phase 2 (lane = d, wave-uniform video).
// Basis is written to LDS in *sorted* order, so phase-2 LDS addresses are
// linear in j (no dependent list->basis chain); CHUNK=512 -> 4 blocks/CU.
// NOTE: no row swizzle — R4's swizzle overlapped rows p (p&7==7) and p+1,
// corrupting 1/8 of rows. Un-swizzled placement conflicts cost ~1 us/CU.

#define V 128
#define D 64
#define K 13
#define CHUNK 512         // n's per block
#define BS 256            // threads per block
#define PER (CHUNK / BS)  // 2 n's per thread in phase 1
#define BST 16            // basis row stride in floats (16B-aligned rows)

__global__ __launch_bounds__(256, 4) void fused_kernel(
    const float* __restrict__ times, const int* __restrict__ ids,
    const float* __restrict__ weights, float* __restrict__ out, int n)
{
    __shared__ float basis[CHUNK * BST];      // 32 KB, sorted rows
    __shared__ int oidx[CHUNK];               // 2 KB: (global_idx<<7)|v, sorted
    __shared__ int cnt[V];
    __shared__ int start[V];
    __shared__ int cur[V];

    int tid = threadIdx.x;
    int base = blockIdx.x * CHUNK;
    int total = n - base; if (total > CHUNK) total = CHUNK;

    if (tid < V) cnt[tid] = 0;
    __syncthreads();

    // ---- Pass A: coalesced loads, count videos (t, v kept in registers) ----
    float myt[PER];
    int myv[PER];
#pragma unroll
    for (int i = 0; i < PER; ++i) {
        int g = base + i * BS + tid;
        myv[i] = -1;
        if (g < n) {
            myt[i] = times[g];
            int v = ids[g];
            myv[i] = v;
            atomicAdd(&cnt[v], 1);
        }
    }
    __syncthreads();

    // ---- Exclusive scan of cnt -> start (Hillis-Steele over 128 bins) ----
    if (tid < V) start[tid] = cnt[tid];
    __syncthreads();
    for (int off = 1; off < V; off <<= 1) {
        int val = 0;
        if (tid < V && tid >= off) val = start[tid - off];
        __syncthreads();
        if (tid < V) start[tid] += val;
        __syncthreads();
    }
    if (tid < V) { start[tid] -= cnt[tid]; cur[tid] = 0; }
    __syncthreads();

    // ---- Pass B: compute basis, write into LDS at sorted position ----
#pragma unroll
    for (int i = 0; i < PER; ++i) {
        if (myv[i] >= 0) {
            int v = myv[i];
            float t = myt[i];
            float s, c;
            __sincosf(3.14159265358979323846f * t, &s, &c);
            float sa[6], ca[6];
            sa[0] = s; ca[0] = c;
#pragma unroll
            for (int j = 1; j < 6; ++j) {     // double-angle recurrence
                sa[j] = 2.0f * sa[j - 1] * ca[j - 1];
                ca[j] = 1.0f - 2.0f * sa[j - 1] * sa[j - 1];
            }
            int r = atomicAdd(&cur[v], 1);
            int pos = start[v] + r;
            float4* bp = (float4*)&basis[pos * BST];
            bp[0] = make_float4(1.0f, sa[0], sa[1], sa[2]);
            bp[1] = make_float4(sa[3], sa[4], sa[5], ca[0]);
            bp[2] = make_float4(ca[1], ca[2], ca[3], ca[4]);
            basis[pos * BST + 12] = ca[5];
            oidx[pos] = ((base + i * BS + tid) << 7) | v;
        }
    }
    __syncthreads();

    // ---- Phase 2: wave-per-n, lane = d. Linear j addressing, uniform reload ----
    int wave = tid >> 6;
    int lane = tid & 63;
    int j0 = wave * (CHUNK / 4);
    int j1 = j0 + (CHUNK / 4); if (j1 > total) j1 = total;

    int vcur = -1;
    float w0, w1, w2, w3, w4, w5, w6, w7, w8, w9, w10, w11, w12;
    w0=w1=w2=w3=w4=w5=w6=w7=w8=w9=w10=w11=w12 = 0.0f;
#pragma unroll 2
    for (int j = j0; j < j1; ++j) {
        int e = oidx[j];                      // broadcast b32, address linear in j
        int v = e & 127;
        const float4* bp = (const float4*)&basis[j * BST];  // broadcast reads
        float4 b0 = bp[0], b1 = bp[1], b2 = bp[2];
        float bk12 = basis[j * BST + 12];
        if (v != vcur) {                      // wave-uniform; ~1 per 4 iters
            vcur = v;
            const float* wp = weights + (v * D + lane) * K;
            w0 = wp[0];  w1 = wp[1];  w2 = wp[2];  w3 = wp[3];
            w4 = wp[4];  w5 = wp[5];  w6 = wp[6];  w7 = wp[7];
            w8 = wp[8];  w9 = wp[9];  w10 = wp[10]; w11 = wp[11]; w12 = wp[12];
        }
        float acc = ((b0.x * w0 + b0.y * w1) + (b0.z * w2 + b0.w * w3))
                  + ((b1.x * w4 + b1.y * w5) + (b1.z * w6 + b1.w * w7))
                  + (((b2.x * w8 + b2.y * w9) + (b2.z * w10 + b2.w * w11))
                     + bk12 * w12);
        out[(long)(e >> 7) * D + lane] = acc; // 256B contiguous per wave
    }
}

extern "C" void kernel_launch(void* const* d_in, const int* in_sizes, int n_in,
                              void* d_out, int out_size, void* d_ws, size_t ws_size,
                              hipStream_t stream) {
    const float* times = (const float*)d_in[0];
    const int* ids = (const int*)d_in[1];
    const float* weights = (const float*)d_in[2];
    float* out = (float*)d_out;
    int n = in_sizes[0];

    int nblk = (n + CHUNK - 1) / CHUNK;   // 782 blocks @ n=400000
    fused_kernel<<<nblk, BS, 0, stream>>>(times, ids, weights, out, n);
}